// Round 2
// baseline (3199.640 us; speedup 1.0000x reference)
//
#include <hip/hip_runtime.h>

// Autoregressive LSTM decoder, torch gate order (i, f, g, o).
// B=262144, P=16, H=32, S=25. One thread per batch element.
// f32 vector baseline: weights via wave-uniform (scalar) loads,
// state fully in registers, 25-step dynamic loop with fully
// unrolled gate/projection body.

constexpr int P = 16;
constexpr int H = 32;
constexpr int S = 25;

typedef float f32x4 __attribute__((ext_vector_type(4)));  // clang vector: ok for nontemporal builtins

__device__ __forceinline__ float sigf(float v) {
    // 1 / (1 + e^-v); v_exp + v_rcp, ~1e-6 rel err
    return __builtin_amdgcn_rcpf(1.0f + __expf(-v));
}

__device__ __forceinline__ float tanh_fast(float v) {
    // 1 - 2/(e^{2v}+1); safe at +/-inf (rcp(inf)=0)
    return 1.0f - 2.0f * __builtin_amdgcn_rcpf(1.0f + __expf(2.0f * v));
}

__global__ __launch_bounds__(256) void decoder_lstm_kernel(
    const float* __restrict__ x0,
    const float* __restrict__ h0,
    const float* __restrict__ c0,
    const float* __restrict__ Wih,   // [4H][P]
    const float* __restrict__ Whh,   // [4H][H]
    const float* __restrict__ bih,   // [4H]
    const float* __restrict__ bhh,   // [4H]
    const float* __restrict__ Wout,  // [P][H]
    const float* __restrict__ bout,  // [P]
    float* __restrict__ out,         // [B][S][P]
    int batch)
{
    const int b = blockIdx.x * blockDim.x + threadIdx.x;
    if (b >= batch) return;

    float x[P], h[H], c[H];

    // Coalesced vector loads of initial state (16B/lane chunks)
    {
        const f32x4* p4 = reinterpret_cast<const f32x4*>(x0) + (size_t)b * (P / 4);
        #pragma unroll
        for (int i = 0; i < P / 4; ++i) {
            f32x4 t = p4[i];
            x[4 * i + 0] = t.x; x[4 * i + 1] = t.y;
            x[4 * i + 2] = t.z; x[4 * i + 3] = t.w;
        }
        const f32x4* h4 = reinterpret_cast<const f32x4*>(h0) + (size_t)b * (H / 4);
        #pragma unroll
        for (int i = 0; i < H / 4; ++i) {
            f32x4 t = h4[i];
            h[4 * i + 0] = t.x; h[4 * i + 1] = t.y;
            h[4 * i + 2] = t.z; h[4 * i + 3] = t.w;
        }
        const f32x4* c4 = reinterpret_cast<const f32x4*>(c0) + (size_t)b * (H / 4);
        #pragma unroll
        for (int i = 0; i < H / 4; ++i) {
            f32x4 t = c4[i];
            c[4 * i + 0] = t.x; c[4 * i + 1] = t.y;
            c[4 * i + 2] = t.z; c[4 * i + 3] = t.w;
        }
    }

    float* o = out + (size_t)b * (S * P);

    for (int s = 0; s < S; ++s) {
        float hn[H];
        #pragma unroll
        for (int j = 0; j < H; ++j) {
            // gate rows: i=j, f=j+H, g=j+2H, o=j+3H  (wave-uniform indices
            // -> compiler emits s_load, weight becomes SGPR operand of fmac)
            float ai = bih[j        ] + bhh[j        ];
            float af = bih[j +     H] + bhh[j +     H];
            float ag = bih[j + 2 * H] + bhh[j + 2 * H];
            float ao = bih[j + 3 * H] + bhh[j + 3 * H];
            #pragma unroll
            for (int k = 0; k < P; ++k) {
                const float xv = x[k];
                ai += Wih[(j        ) * P + k] * xv;
                af += Wih[(j +     H) * P + k] * xv;
                ag += Wih[(j + 2 * H) * P + k] * xv;
                ao += Wih[(j + 3 * H) * P + k] * xv;
            }
            #pragma unroll
            for (int k = 0; k < H; ++k) {
                const float hv = h[k];
                ai += Whh[(j        ) * H + k] * hv;
                af += Whh[(j +     H) * H + k] * hv;
                ag += Whh[(j + 2 * H) * H + k] * hv;
                ao += Whh[(j + 3 * H) * H + k] * hv;
            }
            const float ig = sigf(ai);
            const float fg = sigf(af);
            const float og = sigf(ao);
            const float gg = tanh_fast(ag);
            const float cn = fg * c[j] + ig * gg;
            c[j] = cn;
            hn[j] = og * tanh_fast(cn);
        }
        #pragma unroll
        for (int j = 0; j < H; ++j) h[j] = hn[j];

        // projection back to pose space: x = Wout @ h + bout
        #pragma unroll
        for (int p = 0; p < P; ++p) {
            float acc = bout[p];
            #pragma unroll
            for (int k = 0; k < H; ++k) acc += Wout[p * H + k] * h[k];
            x[p] = acc;
        }

        // streaming store of this step's pose (4x 16B, nontemporal)
        #pragma unroll
        for (int i = 0; i < P / 4; ++i) {
            f32x4 t;
            t.x = x[4 * i + 0]; t.y = x[4 * i + 1];
            t.z = x[4 * i + 2]; t.w = x[4 * i + 3];
            __builtin_nontemporal_store(t, reinterpret_cast<f32x4*>(o + s * P) + i);
        }
    }
}

extern "C" void kernel_launch(void* const* d_in, const int* in_sizes, int n_in,
                              void* d_out, int out_size, void* d_ws, size_t ws_size,
                              hipStream_t stream) {
    const float* x0   = (const float*)d_in[0];
    const float* h0   = (const float*)d_in[1];
    const float* c0   = (const float*)d_in[2];
    const float* Wih  = (const float*)d_in[3];
    const float* Whh  = (const float*)d_in[4];
    const float* bih  = (const float*)d_in[5];
    const float* bhh  = (const float*)d_in[6];
    const float* Wout = (const float*)d_in[7];
    const float* bout = (const float*)d_in[8];
    float* out = (float*)d_out;

    const int batch = in_sizes[0] / P;  // 262144
    dim3 block(256);
    dim3 grid((batch + 255) / 256);
    hipLaunchKernelGGL(decoder_lstm_kernel, grid, block, 0, stream,
                       x0, h0, c0, Wih, Whh, bih, bhh, Wout, bout, out, batch);
}

// Round 3
// 2597.520 us; speedup vs baseline: 1.2318x; 1.2318x over previous
//
#include <hip/hip_runtime.h>

// Autoregressive LSTM decoder, torch gate order (i, f, g, o).
// B=262144, P=16, H=32, S=25. One thread per batch element, f32 VALU.
//
// Key algebraic fusion: for steps s>=1, the input x_s = h_s @ Wout^T + b_out,
// so  gates = h @ (Wout^T Wih^T + Whh^T) + (b_ih + b_hh + Wih @ b_out).
// A tiny setup kernel composes Wcomb[128][32] / bcomb[128] / b0[128] into d_ws.
// This removes x[] from loop-carried state (no spills) and cuts gate FMAs
// from 6144 to 4096 per step.

constexpr int P = 16;
constexpr int H = 32;
constexpr int S = 25;

typedef float f32x4 __attribute__((ext_vector_type(4)));

__device__ __forceinline__ float sigf(float v) {
    return __builtin_amdgcn_rcpf(1.0f + __expf(-v));
}
__device__ __forceinline__ float tanh_fast(float v) {
    return 1.0f - 2.0f * __builtin_amdgcn_rcpf(1.0f + __expf(2.0f * v));
}

// ws layout (floats): Wcomb[4H][H] (4096) | bcomb[4H] (128) | b0[4H] (128)
__global__ void setup_kernel(const float* __restrict__ Wih,
                             const float* __restrict__ Whh,
                             const float* __restrict__ bih,
                             const float* __restrict__ bhh,
                             const float* __restrict__ Wout,
                             const float* __restrict__ bout,
                             float* __restrict__ ws)
{
    const int r = threadIdx.x;  // gate row 0..127
    if (r >= 4 * H) return;
    float* Wc = ws;
    float* bc = ws + 4 * H * H;
    float* b0 = bc + 4 * H;

    for (int k = 0; k < H; ++k) {
        float acc = Whh[r * H + k];
        for (int p = 0; p < P; ++p) acc += Wih[r * P + p] * Wout[p * H + k];
        Wc[r * H + k] = acc;
    }
    const float bb = bih[r] + bhh[r];
    float acc = bb;
    for (int p = 0; p < P; ++p) acc += Wih[r * P + p] * bout[p];
    bc[r] = acc;
    b0[r] = bb;
}

__global__ __launch_bounds__(256, 2) void decoder_main(
    const float* __restrict__ x0,
    const float* __restrict__ h0,
    const float* __restrict__ c0,
    const float* __restrict__ Wih,   // [4H][P] (step 0 only)
    const float* __restrict__ Whh,   // [4H][H] (step 0 only)
    const float* __restrict__ Wout,  // [P][H]
    const float* __restrict__ bout,  // [P]
    const float* __restrict__ ws,    // Wcomb | bcomb | b0
    float* __restrict__ out,         // [B][S][P]
    int batch)
{
    const float* Wc = ws;
    const float* bc = ws + 4 * H * H;
    const float* b0 = bc + 4 * H;

    const int b = blockIdx.x * blockDim.x + threadIdx.x;
    if (b >= batch) return;

    float h[H], c[H];
    {
        const f32x4* h4 = reinterpret_cast<const f32x4*>(h0) + (size_t)b * (H / 4);
        #pragma unroll
        for (int i = 0; i < H / 4; ++i) {
            f32x4 t = h4[i];
            h[4 * i + 0] = t.x; h[4 * i + 1] = t.y;
            h[4 * i + 2] = t.z; h[4 * i + 3] = t.w;
        }
        const f32x4* c4 = reinterpret_cast<const f32x4*>(c0) + (size_t)b * (H / 4);
        #pragma unroll
        for (int i = 0; i < H / 4; ++i) {
            f32x4 t = c4[i];
            c[4 * i + 0] = t.x; c[4 * i + 1] = t.y;
            c[4 * i + 2] = t.z; c[4 * i + 3] = t.w;
        }
    }

    float* op = out + (size_t)b * (S * P);

    // ---------- step 0: gates from (x0, h) via original weights ----------
    {
        float x[P];
        const f32x4* p4 = reinterpret_cast<const f32x4*>(x0) + (size_t)b * (P / 4);
        #pragma unroll
        for (int i = 0; i < P / 4; ++i) {
            f32x4 t = p4[i];
            x[4 * i + 0] = t.x; x[4 * i + 1] = t.y;
            x[4 * i + 2] = t.z; x[4 * i + 3] = t.w;
        }
        float hn[H];
        #pragma unroll
        for (int j = 0; j < H; ++j) {
            float ai = b0[j        ];
            float af = b0[j +     H];
            float ag = b0[j + 2 * H];
            float ao = b0[j + 3 * H];
            #pragma unroll
            for (int k = 0; k < P; ++k) {
                const float xv = x[k];
                ai += Wih[(j        ) * P + k] * xv;
                af += Wih[(j +     H) * P + k] * xv;
                ag += Wih[(j + 2 * H) * P + k] * xv;
                ao += Wih[(j + 3 * H) * P + k] * xv;
            }
            #pragma unroll
            for (int k = 0; k < H; ++k) {
                const float hv = h[k];
                ai += Whh[(j        ) * H + k] * hv;
                af += Whh[(j +     H) * H + k] * hv;
                ag += Whh[(j + 2 * H) * H + k] * hv;
                ao += Whh[(j + 3 * H) * H + k] * hv;
            }
            const float cn = sigf(af) * c[j] + sigf(ai) * tanh_fast(ag);
            c[j] = cn;
            hn[j] = sigf(ao) * tanh_fast(cn);
        }
        #pragma unroll
        for (int j = 0; j < H; ++j) h[j] = hn[j];
    }

    // projection + store for step 0
    {
        #pragma unroll
        for (int i = 0; i < P / 4; ++i) {
            f32x4 t;
            #pragma unroll
            for (int q = 0; q < 4; ++q) {
                const int p = 4 * i + q;
                float a = bout[p];
                #pragma unroll
                for (int k = 0; k < H; ++k) a += Wout[p * H + k] * h[k];
                t[q] = a;
            }
            *(reinterpret_cast<f32x4*>(op) + i) = t;
        }
    }

    // ---------- steps 1..24: gates from h via combined weights ----------
    for (int s = 1; s < S; ++s) {
        float hn[H];
        #pragma unroll
        for (int j = 0; j < H; ++j) {
            float ai = bc[j        ];
            float af = bc[j +     H];
            float ag = bc[j + 2 * H];
            float ao = bc[j + 3 * H];
            #pragma unroll
            for (int k = 0; k < H; ++k) {
                const float hv = h[k];
                ai += Wc[(j        ) * H + k] * hv;
                af += Wc[(j +     H) * H + k] * hv;
                ag += Wc[(j + 2 * H) * H + k] * hv;
                ao += Wc[(j + 3 * H) * H + k] * hv;
            }
            const float cn = sigf(af) * c[j] + sigf(ai) * tanh_fast(ag);
            c[j] = cn;
            hn[j] = sigf(ao) * tanh_fast(cn);
        }
        #pragma unroll
        for (int j = 0; j < H; ++j) h[j] = hn[j];

        #pragma unroll
        for (int i = 0; i < P / 4; ++i) {
            f32x4 t;
            #pragma unroll
            for (int q = 0; q < 4; ++q) {
                const int p = 4 * i + q;
                float a = bout[p];
                #pragma unroll
                for (int k = 0; k < H; ++k) a += Wout[p * H + k] * h[k];
                t[q] = a;
            }
            *(reinterpret_cast<f32x4*>(op + s * P) + i) = t;
        }
    }
}

extern "C" void kernel_launch(void* const* d_in, const int* in_sizes, int n_in,
                              void* d_out, int out_size, void* d_ws, size_t ws_size,
                              hipStream_t stream) {
    const float* x0   = (const float*)d_in[0];
    const float* h0   = (const float*)d_in[1];
    const float* c0   = (const float*)d_in[2];
    const float* Wih  = (const float*)d_in[3];
    const float* Whh  = (const float*)d_in[4];
    const float* bih  = (const float*)d_in[5];
    const float* bhh  = (const float*)d_in[6];
    const float* Wout = (const float*)d_in[7];
    const float* bout = (const float*)d_in[8];
    float* out = (float*)d_out;
    float* ws  = (float*)d_ws;

    const int batch = in_sizes[0] / P;  // 262144

    hipLaunchKernelGGL(setup_kernel, dim3(1), dim3(128), 0, stream,
                       Wih, Whh, bih, bhh, Wout, bout, ws);

    dim3 block(256);
    dim3 grid((batch + 255) / 256);
    hipLaunchKernelGGL(decoder_main, grid, block, 0, stream,
                       x0, h0, c0, Wih, Whh, Wout, bout, ws, out, batch);
}

// Round 4
// 260.883 us; speedup vs baseline: 12.2647x; 9.9567x over previous
//
#include <hip/hip_runtime.h>
#include <hip/hip_bf16.h>

// Autoregressive LSTM decoder via bf16 MFMA, torch gate order (i,f,g,o).
// B=262144, P=16, H=32, S=25.  One wave = 32 batch rows.
// Weights live in 60 VGPRs as pre-built MFMA A-fragments (setup kernel).
// Round-2 fusion retained: gates_s = Waug·[h;1],  Waug = [Wcomb|bc ; Wout|bout].
// Cell state + elementwise stay in f32 in the MFMA D-layout; h is re-packed
// to the B-fragment layout each step with 8 shfl_xor(32) + selects.

constexpr int P = 16;
constexpr int H = 32;
constexpr int S = 25;

typedef short        bf16x8 __attribute__((ext_vector_type(8)));
typedef float        f32x16 __attribute__((ext_vector_type(16)));
typedef float        f32x4  __attribute__((ext_vector_type(4)));
typedef unsigned int u32x4  __attribute__((ext_vector_type(4)));

union FragU { u32x4 u; bf16x8 b; };

__device__ __forceinline__ unsigned int pkbf(float lo, float hi) {
    unsigned short a = __builtin_bit_cast(unsigned short, __float2bfloat16(lo));
    unsigned short b = __builtin_bit_cast(unsigned short, __float2bfloat16(hi));
    return (unsigned int)a | ((unsigned int)b << 16);
}

__device__ __forceinline__ float sigf(float v) {
    return __builtin_amdgcn_rcpf(1.0f + __expf(-v));
}
__device__ __forceinline__ float tanh_fast(float v) {
    return 1.0f - 2.0f * __builtin_amdgcn_rcpf(1.0f + __expf(2.0f * v));
}

// ---------------- setup: build bf16 A-fragments into ws -------------------
// steady W_aug[160][48]: r<128: Wcomb=Whh+Wih·Wout (k<32), bias bc at k=32;
//                        128<=r<144: Wout rows, bout at k=32;  r>=144: 0.
// step0  W0_aug[128][64]: k<16: Wih; 16<=k<48: Whh; k=48: b_ih+b_hh; else 0.
// word index: steady  ((t*3+c)*64 + lane)*4 + v        (t<5, c<3)
//             step0   3840 + ((t*4+c)*64 + lane)*4 + v (t<4, c<4)
// A-frag mapping assumed: row m = 32t + (lane&31); k = 16c + 8*(lane>>5) + 2v (+1 in hi16).
// (Any k-permutation error cancels: B-frags are built with the same mapping.)
__global__ void setup_frags(const float* __restrict__ Wih, const float* __restrict__ Whh,
                            const float* __restrict__ bih, const float* __restrict__ bhh,
                            const float* __restrict__ Wout, const float* __restrict__ bout,
                            unsigned int* __restrict__ ws)
{
    auto waug = [&](int r, int k) -> float {
        if (r < 128) {
            if (k < 32) {
                float a = Whh[r * H + k];
                for (int p = 0; p < P; ++p) a += Wih[r * P + p] * Wout[p * H + k];
                return a;
            }
            if (k == 32) {
                float a = bih[r] + bhh[r];
                for (int p = 0; p < P; ++p) a += Wih[r * P + p] * bout[p];
                return a;
            }
            return 0.0f;
        } else if (r < 144) {
            int p = r - 128;
            if (k < 32)  return Wout[p * H + k];
            if (k == 32) return bout[p];
            return 0.0f;
        }
        return 0.0f;
    };
    auto w0aug = [&](int r, int k) -> float {
        if (k < 16) return Wih[r * P + k];
        if (k < 48) return Whh[r * H + (k - 16)];
        if (k == 48) return bih[r] + bhh[r];
        return 0.0f;
    };

    const int tid = threadIdx.x;
    for (int idx = tid; idx < 5 * 3 * 64 * 4; idx += 256) {
        int v = idx & 3, l = (idx >> 2) & 63, tc = idx >> 8;
        int t = tc / 3, c = tc % 3;
        int r = 32 * t + (l & 31);
        int k = 16 * c + 8 * (l >> 5) + 2 * v;
        ws[idx] = pkbf(waug(r, k), waug(r, k + 1));
    }
    for (int idx = tid; idx < 4 * 4 * 64 * 4; idx += 256) {
        int v = idx & 3, l = (idx >> 2) & 63, tc = idx >> 8;
        int t = tc / 4, c = tc % 4;
        int r = 32 * t + (l & 31);
        int k = 16 * c + 8 * (l >> 5) + 2 * v;
        ws[3840 + idx] = pkbf(w0aug(r, k), w0aug(r, k + 1));
    }
}

// ------------------------------- main -------------------------------------
__global__ __launch_bounds__(256, 2) void decoder_mfma(
    const float* __restrict__ x0, const float* __restrict__ h0,
    const float* __restrict__ c0, const unsigned int* __restrict__ ws,
    float* __restrict__ out, int batch)
{
    const int lane = threadIdx.x & 63;
    const int wid  = threadIdx.x >> 6;
    const int bcol = lane & 31;
    const int hi   = lane >> 5;
    const int bg   = (blockIdx.x * 4 + wid) * 32 + bcol;  // this lane's batch row
    if (bg >= batch) return;  // batch % 128 == 0: wave-uniform, never partial

    // steady A-fragments: 5 tiles (4 gate quarters + proj) x 3 K-chunks
    FragU A[5][3];
    #pragma unroll
    for (int t = 0; t < 5; ++t)
        #pragma unroll
        for (int c = 0; c < 3; ++c)
            A[t][c].u = *reinterpret_cast<const u32x4*>(ws + ((t * 3 + c) * 64 + lane) * 4);

    // bias chunk B-frag: k=+0 slot = bf16(1.0) for hi==0 lanes, else 0
    FragU Bbias;
    Bbias.u.x = (hi == 0) ? 0x3F80u : 0u;
    Bbias.u.y = 0u; Bbias.u.z = 0u; Bbias.u.w = 0u;

    // cell state in D-layout: cc[r] <-> c[bg][(r&3) + 8*(r>>2) + 4*hi]
    float cc[16];
    #pragma unroll
    for (int q = 0; q < 4; ++q) {
        f32x4 t = *reinterpret_cast<const f32x4*>(c0 + (size_t)bg * H + q * 8 + 4 * hi);
        cc[q * 4 + 0] = t.x; cc[q * 4 + 1] = t.y; cc[q * 4 + 2] = t.z; cc[q * 4 + 3] = t.w;
    }

    const f32x16 vzero = {};
    f32x16 acc[4];

    // ---- step-0 gates: K = [x0(16) | h0(32) | 1], W0_aug fragments ----
    {
        FragU B0[4];
        {
            const float* p = x0 + (size_t)bg * P + 8 * hi;
            f32x4 a = *reinterpret_cast<const f32x4*>(p);
            f32x4 b = *reinterpret_cast<const f32x4*>(p + 4);
            B0[0].u.x = pkbf(a.x, a.y); B0[0].u.y = pkbf(a.z, a.w);
            B0[0].u.z = pkbf(b.x, b.y); B0[0].u.w = pkbf(b.z, b.w);
        }
        #pragma unroll
        for (int cch = 0; cch < 2; ++cch) {
            const float* p = h0 + (size_t)bg * H + 16 * cch + 8 * hi;
            f32x4 a = *reinterpret_cast<const f32x4*>(p);
            f32x4 b = *reinterpret_cast<const f32x4*>(p + 4);
            B0[1 + cch].u.x = pkbf(a.x, a.y); B0[1 + cch].u.y = pkbf(a.z, a.w);
            B0[1 + cch].u.z = pkbf(b.x, b.y); B0[1 + cch].u.w = pkbf(b.z, b.w);
        }
        B0[3] = Bbias;

        #pragma unroll
        for (int t = 0; t < 4; ++t) acc[t] = vzero;
        #pragma unroll
        for (int c4 = 0; c4 < 4; ++c4) {
            #pragma unroll
            for (int t = 0; t < 4; ++t) {
                FragU a;
                a.u = *reinterpret_cast<const u32x4*>(ws + 3840 + ((t * 4 + c4) * 64 + lane) * 4);
                acc[t] = __builtin_amdgcn_mfma_f32_32x32x16_bf16(a.b, B0[c4].b, acc[t], 0, 0, 0);
            }
        }
    }

    FragU Bh[2];
    for (int s = 0; s < S; ++s) {
        // elementwise cell update (tile t = gate quarter: 0=i,1=f,2=g,3=o)
        float hreg[16];
        #pragma unroll
        for (int r = 0; r < 16; ++r) {
            float gi = acc[0][r], gf = acc[1][r], gg = acc[2][r], go = acc[3][r];
            float cn = sigf(gf) * cc[r] + sigf(gi) * tanh_fast(gg);
            cc[r] = cn;
            hreg[r] = sigf(go) * tanh_fast(cn);
        }

        // h -> B-fragment: pack bf16 pairs, exchange quads across hi-halves
        unsigned int w[8], pw[8];
        #pragma unroll
        for (int q = 0; q < 4; ++q) {
            w[2 * q]     = pkbf(hreg[4 * q + 0], hreg[4 * q + 1]);
            w[2 * q + 1] = pkbf(hreg[4 * q + 2], hreg[4 * q + 3]);
        }
        #pragma unroll
        for (int i = 0; i < 8; ++i) pw[i] = __shfl_xor(w[i], 32);
        Bh[0].u.x = hi ? pw[2] : w[0];  Bh[0].u.y = hi ? pw[3] : w[1];
        Bh[0].u.z = hi ? w[2]  : pw[0]; Bh[0].u.w = hi ? w[3]  : pw[1];
        Bh[1].u.x = hi ? pw[6] : w[4];  Bh[1].u.y = hi ? pw[7] : w[5];
        Bh[1].u.z = hi ? w[6]  : pw[4]; Bh[1].u.w = hi ? w[7]  : pw[5];

        // projection tile: x_s = Wout·h_new + bout
        f32x16 px = vzero;
        px = __builtin_amdgcn_mfma_f32_32x32x16_bf16(A[4][0].b, Bh[0].b,  px, 0, 0, 0);
        px = __builtin_amdgcn_mfma_f32_32x32x16_bf16(A[4][1].b, Bh[1].b,  px, 0, 0, 0);
        px = __builtin_amdgcn_mfma_f32_32x32x16_bf16(A[4][2].b, Bbias.b, px, 0, 0, 0);

        // store x_s: regs 0..7 hold p = 8q + 4hi + (0..3), q=0,1 (NT, no RFO)
        float* op = out + ((size_t)bg * S + s) * P + 4 * hi;
        f32x4 v0; v0.x = px[0]; v0.y = px[1]; v0.z = px[2]; v0.w = px[3];
        f32x4 v1; v1.x = px[4]; v1.y = px[5]; v1.z = px[6]; v1.w = px[7];
        __builtin_nontemporal_store(v0, reinterpret_cast<f32x4*>(op));
        __builtin_nontemporal_store(v1, reinterpret_cast<f32x4*>(op + 8));

        // next step's gates from h_new (combined weights, bias via chunk 2)
        if (s + 1 < S) {
            #pragma unroll
            for (int t = 0; t < 4; ++t) acc[t] = vzero;
            #pragma unroll
            for (int cch = 0; cch < 2; ++cch)
                #pragma unroll
                for (int t = 0; t < 4; ++t)
                    acc[t] = __builtin_amdgcn_mfma_f32_32x32x16_bf16(A[t][cch].b, Bh[cch].b, acc[t], 0, 0, 0);
            #pragma unroll
            for (int t = 0; t < 4; ++t)
                acc[t] = __builtin_amdgcn_mfma_f32_32x32x16_bf16(A[t][2].b, Bbias.b, acc[t], 0, 0, 0);
        }
    }
}

extern "C" void kernel_launch(void* const* d_in, const int* in_sizes, int n_in,
                              void* d_out, int out_size, void* d_ws, size_t ws_size,
                              hipStream_t stream) {
    const float* x0   = (const float*)d_in[0];
    const float* h0   = (const float*)d_in[1];
    const float* c0   = (const float*)d_in[2];
    const float* Wih  = (const float*)d_in[3];
    const float* Whh  = (const float*)d_in[4];
    const float* bih  = (const float*)d_in[5];
    const float* bhh  = (const float*)d_in[6];
    const float* Wout = (const float*)d_in[7];
    const float* bout = (const float*)d_in[8];
    float* out = (float*)d_out;
    unsigned int* ws = (unsigned int*)d_ws;

    const int batch = in_sizes[0] / P;  // 262144

    hipLaunchKernelGGL(setup_frags, dim3(1), dim3(256), 0, stream,
                       Wih, Whh, bih, bhh, Wout, bout, ws);

    dim3 block(256);                       // 4 waves x 32 batch rows = 128 batch/block
    dim3 grid((batch + 127) / 128);        // 2048 blocks
    hipLaunchKernelGGL(decoder_mfma, grid, block, 0, stream,
                       x0, h0, c0, ws, out, batch);
}

// Round 6
// 228.438 us; speedup vs baseline: 14.0066x; 1.1420x over previous
//
#include <hip/hip_runtime.h>
#include <hip/hip_bf16.h>

// Autoregressive LSTM decoder via bf16 MFMA, torch gate order (i,f,g,o).
// B=262144, P=16, H=32, S=25.  One wave = 32 batch rows.
//
// Round-5 structure:
//  * k-permutation chosen so the D-layout h-values ARE the B-fragment values
//    (no cross-lane exchange; A fragments built with the same permutation,
//    which cancels -- dot products are k-permutation invariant).
//  * exp2 scale (-log2e for i,f,o rows; -2log2e for g rows) folded into the
//    A-matrix at setup; elementwise uses v_exp_f32 directly.
//  * shared-denominator sigmoid*tanh forms: 5 exp + 3 rcp per row.

constexpr int P = 16;
constexpr int H = 32;
constexpr int S = 25;

typedef short        bf16x8 __attribute__((ext_vector_type(8)));
typedef float        f32x16 __attribute__((ext_vector_type(16)));
typedef float        f32x4  __attribute__((ext_vector_type(4)));
typedef unsigned int u32x4  __attribute__((ext_vector_type(4)));

union FragU { u32x4 u; bf16x8 b; };

#if __has_builtin(__builtin_amdgcn_exp2f)
#define EX2 __builtin_amdgcn_exp2f
#else
#define EX2 exp2f
#endif

__device__ __forceinline__ unsigned int pkbf(float lo, float hi) {
    unsigned short a = __builtin_bit_cast(unsigned short, __float2bfloat16(lo));
    unsigned short b = __builtin_bit_cast(unsigned short, __float2bfloat16(hi));
    return (unsigned int)a | ((unsigned int)b << 16);
}

// gate-row exp2 scale: rows [0,32)=i, [32,64)=f, [64,96)=g, [96,128)=o
__device__ __forceinline__ float gate_scale(int r) {
    return (r >= 64 && r < 96) ? -2.8853900817779268f   // g rows: -2*log2(e)
                               : -1.4426950408889634f;  // i,f,o rows: -log2(e)
}

// ---------------- setup: build bf16 A-fragments into ws -------------------
// logical matrices:
//  steady W_aug[160][48]: r<128: Wcomb=Whh+Wih*Wout (k<32), bias at k=32, 0 pad;
//                         128<=r<144: Wout rows, bout at k=32; r>=144: 0.
//                         gate rows (r<128) scaled by gate_scale(r).
//  step0  W0_aug[128][64]: k<16: Wih; 16<=k<48: Whh; k=48: b_ih+b_hh; 0 pad.
//                         all rows scaled by gate_scale(r).
// fragment slot (c = 16-wide K chunk, lane half hi, word v, half b):
//   logical k = 16c + 8*(v>>1) + 4*hi + 2*(v&1) + b
// word index: steady ((t*3+c)*64 + lane)*4 + v   (t<5,c<3)
//             step0  3840 + ((t*4+c)*64 + lane)*4 + v  (t<4,c<4)
__global__ void setup_frags(const float* __restrict__ Wih, const float* __restrict__ Whh,
                            const float* __restrict__ bih, const float* __restrict__ bhh,
                            const float* __restrict__ Wout, const float* __restrict__ bout,
                            unsigned int* __restrict__ ws)
{
    auto waug = [&](int r, int k) -> float {
        float s = (r < 128) ? gate_scale(r) : 1.0f;
        if (r < 128) {
            if (k < 32) {
                float a = Whh[r * H + k];
                for (int p = 0; p < P; ++p) a += Wih[r * P + p] * Wout[p * H + k];
                return s * a;
            }
            if (k == 32) {
                float a = bih[r] + bhh[r];
                for (int p = 0; p < P; ++p) a += Wih[r * P + p] * bout[p];
                return s * a;
            }
            return 0.0f;
        } else if (r < 144) {
            int p = r - 128;
            if (k < 32)  return Wout[p * H + k];
            if (k == 32) return bout[p];
            return 0.0f;
        }
        return 0.0f;
    };
    auto w0aug = [&](int r, int k) -> float {
        float s = gate_scale(r);
        if (k < 16)  return s * Wih[r * P + k];
        if (k < 48)  return s * Whh[r * H + (k - 16)];
        if (k == 48) return s * (bih[r] + bhh[r]);
        return 0.0f;
    };

    const int tid = threadIdx.x;
    for (int idx = tid; idx < 5 * 3 * 64 * 4; idx += 256) {
        int v = idx & 3, l = (idx >> 2) & 63, tc = idx >> 8;
        int t = tc / 3, c = tc % 3;
        int r = 32 * t + (l & 31);
        int k = 16 * c + 8 * (v >> 1) + 4 * (l >> 5) + 2 * (v & 1);
        ws[idx] = pkbf(waug(r, k), waug(r, k + 1));
    }
    for (int idx = tid; idx < 4 * 4 * 64 * 4; idx += 256) {
        int v = idx & 3, l = (idx >> 2) & 63, tc = idx >> 8;
        int t = tc / 4, c = tc % 4;
        int r = 32 * t + (l & 31);
        int k = 16 * c + 8 * (v >> 1) + 4 * (l >> 5) + 2 * (v & 1);
        ws[3840 + idx] = pkbf(w0aug(r, k), w0aug(r, k + 1));
    }
}

// ------------------------------- main -------------------------------------
__global__ __launch_bounds__(256, 2) void decoder_mfma(
    const float* __restrict__ x0, const float* __restrict__ h0,
    const float* __restrict__ c0, const unsigned int* __restrict__ ws,
    float* __restrict__ out, int batch)
{
    const int lane = threadIdx.x & 63;
    const int wid  = threadIdx.x >> 6;
    const int bcol = lane & 31;
    const int hi   = lane >> 5;
    const int bg   = (blockIdx.x * 4 + wid) * 32 + bcol;  // this lane's batch row
    if (bg >= batch) return;  // batch % 128 == 0: wave-uniform

    // steady A-fragments: 5 tiles (4 gate quarters + proj) x 3 K-chunks
    FragU A[5][3];
    #pragma unroll
    for (int t = 0; t < 5; ++t)
        #pragma unroll
        for (int c = 0; c < 3; ++c)
            A[t][c].u = *reinterpret_cast<const u32x4*>(ws + ((t * 3 + c) * 64 + lane) * 4);

    // bias B-chunk: logical k=32 (steady) / k=48 (step0) lives at (hi=0, v=0, lo)
    FragU Bbias;
    Bbias.u.x = (hi == 0) ? 0x3F80u : 0u;  // bf16(1.0)
    Bbias.u.y = 0u; Bbias.u.z = 0u; Bbias.u.w = 0u;

    // cell state in D-layout: cc[r] <-> c[bg][(r&3) + 8*(r>>2) + 4*hi]
    float cc[16];
    #pragma unroll
    for (int q = 0; q < 4; ++q) {
        f32x4 t = *reinterpret_cast<const f32x4*>(c0 + (size_t)bg * H + q * 8 + 4 * hi);
        cc[q * 4 + 0] = t.x; cc[q * 4 + 1] = t.y; cc[q * 4 + 2] = t.z; cc[q * 4 + 3] = t.w;
    }

    const f32x16 vzero = {};
    f32x16 acc[4];

    // ---- step-0 gates: K = [x0(16) | h0(32) | 1], W0_aug fragments ----
    {
        FragU B0[4];
        {
            const float* p = x0 + (size_t)bg * P;
            f32x4 a  = *reinterpret_cast<const f32x4*>(p + 4 * hi);
            f32x4 b4 = *reinterpret_cast<const f32x4*>(p + 8 + 4 * hi);
            B0[0].u.x = pkbf(a.x, a.y);  B0[0].u.y = pkbf(a.z, a.w);
            B0[0].u.z = pkbf(b4.x, b4.y); B0[0].u.w = pkbf(b4.z, b4.w);
        }
        #pragma unroll
        for (int ch = 0; ch < 2; ++ch) {
            const float* p = h0 + (size_t)bg * H + 16 * ch;
            f32x4 a  = *reinterpret_cast<const f32x4*>(p + 4 * hi);
            f32x4 b4 = *reinterpret_cast<const f32x4*>(p + 8 + 4 * hi);
            B0[1 + ch].u.x = pkbf(a.x, a.y);  B0[1 + ch].u.y = pkbf(a.z, a.w);
            B0[1 + ch].u.z = pkbf(b4.x, b4.y); B0[1 + ch].u.w = pkbf(b4.z, b4.w);
        }
        B0[3] = Bbias;

        #pragma unroll
        for (int t = 0; t < 4; ++t) acc[t] = vzero;
        #pragma unroll
        for (int c4 = 0; c4 < 4; ++c4) {
            #pragma unroll
            for (int t = 0; t < 4; ++t) {
                FragU a;
                a.u = *reinterpret_cast<const u32x4*>(ws + 3840 + ((t * 4 + c4) * 64 + lane) * 4);
                acc[t] = __builtin_amdgcn_mfma_f32_32x32x16_bf16(a.b, B0[c4].b, acc[t], 0, 0, 0);
            }
        }
    }

    FragU Bh[2];
    for (int s = 0; s < S; ++s) {
        // elementwise cell update. acc[0]=Fi, acc[1]=Ff, acc[2]=Fg, acc[3]=Fo
        // where F* are exp2-ready: Fi = -i*log2e, Fg = -2g*log2e, etc.
        float hh[16];
        #pragma unroll
        for (int r = 0; r < 16; ++r) {
            const float ei = EX2(acc[0][r]);        // e^{-i}
            const float ef = EX2(acc[1][r]);        // e^{-f}
            const float eg = EX2(acc[2][r]);        // e^{-2g}
            const float eo = EX2(acc[3][r]);        // e^{-o}
            const float r1 = __builtin_amdgcn_rcpf((1.0f + ei) * (1.0f + eg));
            const float tg = (1.0f - eg) * r1;      // sig(i)*tanh(g)
            const float rf = __builtin_amdgcn_rcpf(1.0f + ef);
            const float cn = __builtin_fmaf(cc[r], rf, tg);
            cc[r] = cn;
            const float ec = EX2(cn * -2.8853900817779268f);  // e^{-2cn}
            const float r2 = __builtin_amdgcn_rcpf((1.0f + ec) * (1.0f + eo));
            hh[r] = (1.0f - ec) * r2;               // sig(o)*tanh(cn)
        }

        // h -> B-fragments: with the chosen k-permutation each lane's B slots
        // are exactly its own D-layout values -> pure sequential pack.
        Bh[0].u.x = pkbf(hh[0],  hh[1]);  Bh[0].u.y = pkbf(hh[2],  hh[3]);
        Bh[0].u.z = pkbf(hh[4],  hh[5]);  Bh[0].u.w = pkbf(hh[6],  hh[7]);
        Bh[1].u.x = pkbf(hh[8],  hh[9]);  Bh[1].u.y = pkbf(hh[10], hh[11]);
        Bh[1].u.z = pkbf(hh[12], hh[13]); Bh[1].u.w = pkbf(hh[14], hh[15]);

        // projection tile: x_s = Wout*h_new + bout
        f32x16 px;
        px = __builtin_amdgcn_mfma_f32_32x32x16_bf16(A[4][2].b, Bbias.b, vzero, 0, 0, 0);
        px = __builtin_amdgcn_mfma_f32_32x32x16_bf16(A[4][0].b, Bh[0].b, px,    0, 0, 0);
        px = __builtin_amdgcn_mfma_f32_32x32x16_bf16(A[4][1].b, Bh[1].b, px,    0, 0, 0);

        // store x_s: regs 0..7 hold pose dims p = 8q + 4hi + (0..3), q=0,1
        float* op = out + ((size_t)bg * S + s) * P + 4 * hi;
        f32x4 v0; v0.x = px[0]; v0.y = px[1]; v0.z = px[2]; v0.w = px[3];
        f32x4 v1; v1.x = px[4]; v1.y = px[5]; v1.z = px[6]; v1.w = px[7];
        __builtin_nontemporal_store(v0, reinterpret_cast<f32x4*>(op));
        __builtin_nontemporal_store(v1, reinterpret_cast<f32x4*>(op + 8));

        // next step's gates from h_new (combined weights; bias chunk first)
        if (s + 1 < S) {
            #pragma unroll
            for (int t = 0; t < 4; ++t)
                acc[t] = __builtin_amdgcn_mfma_f32_32x32x16_bf16(A[t][2].b, Bbias.b, vzero, 0, 0, 0);
            #pragma unroll
            for (int ch = 0; ch < 2; ++ch)
                #pragma unroll
                for (int t = 0; t < 4; ++t)
                    acc[t] = __builtin_amdgcn_mfma_f32_32x32x16_bf16(A[t][ch].b, Bh[ch].b, acc[t], 0, 0, 0);
        }
    }
}

extern "C" void kernel_launch(void* const* d_in, const int* in_sizes, int n_in,
                              void* d_out, int out_size, void* d_ws, size_t ws_size,
                              hipStream_t stream) {
    const float* x0   = (const float*)d_in[0];
    const float* h0   = (const float*)d_in[1];
    const float* c0   = (const float*)d_in[2];
    const float* Wih  = (const float*)d_in[3];
    const float* Whh  = (const float*)d_in[4];
    const float* bih  = (const float*)d_in[5];
    const float* bhh  = (const float*)d_in[6];
    const float* Wout = (const float*)d_in[7];
    const float* bout = (const float*)d_in[8];
    float* out = (float*)d_out;
    unsigned int* ws = (unsigned int*)d_ws;

    const int batch = in_sizes[0] / P;  // 262144

    hipLaunchKernelGGL(setup_frags, dim3(1), dim3(256), 0, stream,
                       Wih, Whh, bih, bhh, Wout, bout, ws);

    dim3 block(256);                    // 4 waves x 32 batch rows = 128 batch/block
    dim3 grid((batch + 127) / 128);     // 2048 blocks
    hipLaunchKernelGGL(decoder_mfma, grid, block, 0, stream,
                       x0, h0, c0, ws, out, batch);
}

// Round 7
// 224.943 us; speedup vs baseline: 14.2242x; 1.0155x over previous
//
#include <hip/hip_runtime.h>
#include <hip/hip_bf16.h>

// Autoregressive LSTM decoder via bf16 MFMA, torch gate order (i,f,g,o).
// B=262144, P=16, H=32, S=25.  One wave = TWO independent 32-batch tiles
// (ILP-2): two recurrence chains interleaved to cover MFMA/trans latency,
// since wave residency (~2.3/SIMD) is too low to hide it with TLP.
//
// Carried from round 5/6:
//  * k-permutation chosen so D-layout h-values ARE the B-fragment values
//    (no cross-lane exchange; A built with the same permutation -> cancels).
//  * exp2 scales folded into A at setup; elementwise uses v_exp_f32 directly.
//  * shared-denominator sigmoid*tanh: 5 exp + 3 rcp per element.

constexpr int P = 16;
constexpr int H = 32;
constexpr int S = 25;

typedef short        bf16x8 __attribute__((ext_vector_type(8)));
typedef float        f32x16 __attribute__((ext_vector_type(16)));
typedef float        f32x4  __attribute__((ext_vector_type(4)));
typedef unsigned int u32x4  __attribute__((ext_vector_type(4)));

union FragU { u32x4 u; bf16x8 b; };

#if __has_builtin(__builtin_amdgcn_exp2f)
#define EX2 __builtin_amdgcn_exp2f
#else
#define EX2 exp2f
#endif

__device__ __forceinline__ unsigned int pkbf(float lo, float hi) {
    unsigned short a = __builtin_bit_cast(unsigned short, __float2bfloat16(lo));
    unsigned short b = __builtin_bit_cast(unsigned short, __float2bfloat16(hi));
    return (unsigned int)a | ((unsigned int)b << 16);
}

// gate-row exp2 scale: rows [0,32)=i, [32,64)=f, [64,96)=g, [96,128)=o
__device__ __forceinline__ float gate_scale(int r) {
    return (r >= 64 && r < 96) ? -2.8853900817779268f   // g rows: -2*log2(e)
                               : -1.4426950408889634f;  // i,f,o rows: -log2(e)
}

// ---------------- setup: build bf16 A-fragments into ws -------------------
// steady W_aug[160][48]: r<128: Wcomb=Whh+Wih*Wout (k<32), bias at k=32, 0 pad;
//                        128<=r<144: Wout rows, bout at k=32; r>=144: 0.
//                        gate rows (r<128) scaled by gate_scale(r).
// step0  W0_aug[128][64]: k<16: Wih; 16<=k<48: Whh; k=48: b_ih+b_hh; 0 pad.
// fragment slot: logical k = 16c + 8*(v>>1) + 4*hi + 2*(v&1) + b
// word index: steady ((t*3+c)*64 + lane)*4 + v   (t<5,c<3)
//             step0  3840 + ((t*4+c)*64 + lane)*4 + v  (t<4,c<4)
__global__ void setup_frags(const float* __restrict__ Wih, const float* __restrict__ Whh,
                            const float* __restrict__ bih, const float* __restrict__ bhh,
                            const float* __restrict__ Wout, const float* __restrict__ bout,
                            unsigned int* __restrict__ ws)
{
    auto waug = [&](int r, int k) -> float {
        float s = (r < 128) ? gate_scale(r) : 1.0f;
        if (r < 128) {
            if (k < 32) {
                float a = Whh[r * H + k];
                for (int p = 0; p < P; ++p) a += Wih[r * P + p] * Wout[p * H + k];
                return s * a;
            }
            if (k == 32) {
                float a = bih[r] + bhh[r];
                for (int p = 0; p < P; ++p) a += Wih[r * P + p] * bout[p];
                return s * a;
            }
            return 0.0f;
        } else if (r < 144) {
            int p = r - 128;
            if (k < 32)  return Wout[p * H + k];
            if (k == 32) return bout[p];
            return 0.0f;
        }
        return 0.0f;
    };
    auto w0aug = [&](int r, int k) -> float {
        float s = gate_scale(r);
        if (k < 16)  return s * Wih[r * P + k];
        if (k < 48)  return s * Whh[r * H + (k - 16)];
        if (k == 48) return s * (bih[r] + bhh[r]);
        return 0.0f;
    };

    const int tid = threadIdx.x;
    for (int idx = tid; idx < 5 * 3 * 64 * 4; idx += 256) {
        int v = idx & 3, l = (idx >> 2) & 63, tc = idx >> 8;
        int t = tc / 3, c = tc % 3;
        int r = 32 * t + (l & 31);
        int k = 16 * c + 8 * (v >> 1) + 4 * (l >> 5) + 2 * (v & 1);
        ws[idx] = pkbf(waug(r, k), waug(r, k + 1));
    }
    for (int idx = tid; idx < 4 * 4 * 64 * 4; idx += 256) {
        int v = idx & 3, l = (idx >> 2) & 63, tc = idx >> 8;
        int t = tc / 4, c = tc % 4;
        int r = 32 * t + (l & 31);
        int k = 16 * c + 8 * (v >> 1) + 4 * (l >> 5) + 2 * (v & 1);
        ws[3840 + idx] = pkbf(w0aug(r, k), w0aug(r, k + 1));
    }
}

// ------------------------------- main -------------------------------------
__global__ __launch_bounds__(256, 2) void decoder_mfma(
    const float* __restrict__ x0, const float* __restrict__ h0,
    const float* __restrict__ c0, const unsigned int* __restrict__ ws,
    float* __restrict__ out, int batch)
{
    const int lane = threadIdx.x & 63;
    const int wid  = threadIdx.x >> 6;
    const int bcol = lane & 31;
    const int hi   = lane >> 5;
    const int base = (blockIdx.x * 4 + wid) * 64;   // 64 batch rows per wave
    const int bg0  = base + bcol;
    const int bg1  = base + 32 + bcol;
    if (bg1 >= batch) return;  // batch % 256 == 0: wave-uniform

    // steady A-fragments: 5 tiles (4 gate quarters + proj) x 3 K-chunks
    FragU A[5][3];
    #pragma unroll
    for (int t = 0; t < 5; ++t)
        #pragma unroll
        for (int c = 0; c < 3; ++c)
            A[t][c].u = *reinterpret_cast<const u32x4*>(ws + ((t * 3 + c) * 64 + lane) * 4);

    // bias B-chunk: logical k=32 (steady) / k=48 (step0) at (hi=0, v=0, lo half)
    FragU Bbias;
    Bbias.u.x = (hi == 0) ? 0x3F80u : 0u;  // bf16(1.0)
    Bbias.u.y = 0u; Bbias.u.z = 0u; Bbias.u.w = 0u;

    const int bgs[2] = { bg0, bg1 };

    // cell state in D-layout: cc[u][r] <-> c[bg_u][(r&3) + 8*(r>>2) + 4*hi]
    float cc[2][16];
    #pragma unroll
    for (int u = 0; u < 2; ++u)
        #pragma unroll
        for (int q = 0; q < 4; ++q) {
            f32x4 t = *reinterpret_cast<const f32x4*>(c0 + (size_t)bgs[u] * H + q * 8 + 4 * hi);
            cc[u][q * 4 + 0] = t.x; cc[u][q * 4 + 1] = t.y;
            cc[u][q * 4 + 2] = t.z; cc[u][q * 4 + 3] = t.w;
        }

    const f32x16 vzero = {};
    f32x16 acc[2][4];

    // ---- step-0 gates: K = [x0(16) | h0(32) | 1], W0_aug fragments ----
    {
        FragU B0[2][4];
        #pragma unroll
        for (int u = 0; u < 2; ++u) {
            const float* p = x0 + (size_t)bgs[u] * P;
            f32x4 a  = *reinterpret_cast<const f32x4*>(p + 4 * hi);
            f32x4 b4 = *reinterpret_cast<const f32x4*>(p + 8 + 4 * hi);
            B0[u][0].u.x = pkbf(a.x, a.y);   B0[u][0].u.y = pkbf(a.z, a.w);
            B0[u][0].u.z = pkbf(b4.x, b4.y); B0[u][0].u.w = pkbf(b4.z, b4.w);
            #pragma unroll
            for (int ch = 0; ch < 2; ++ch) {
                const float* q = h0 + (size_t)bgs[u] * H + 16 * ch;
                f32x4 c4 = *reinterpret_cast<const f32x4*>(q + 4 * hi);
                f32x4 d4 = *reinterpret_cast<const f32x4*>(q + 8 + 4 * hi);
                B0[u][1 + ch].u.x = pkbf(c4.x, c4.y); B0[u][1 + ch].u.y = pkbf(c4.z, c4.w);
                B0[u][1 + ch].u.z = pkbf(d4.x, d4.y); B0[u][1 + ch].u.w = pkbf(d4.z, d4.w);
            }
            B0[u][3] = Bbias;
            #pragma unroll
            for (int t = 0; t < 4; ++t) acc[u][t] = vzero;
        }
        #pragma unroll
        for (int c4 = 0; c4 < 4; ++c4)
            #pragma unroll
            for (int t = 0; t < 4; ++t) {
                FragU a;  // shared between both tiles
                a.u = *reinterpret_cast<const u32x4*>(ws + 3840 + ((t * 4 + c4) * 64 + lane) * 4);
                #pragma unroll
                for (int u = 0; u < 2; ++u)
                    acc[u][t] = __builtin_amdgcn_mfma_f32_32x32x16_bf16(a.b, B0[u][c4].b, acc[u][t], 0, 0, 0);
            }
    }

    FragU Bh[2][2];
    for (int s = 0; s < S; ++s) {
        // elementwise cell update, both tiles (32 independent rows of ILP).
        // acc[u][0]=Fi, [1]=Ff, [2]=Fg, [3]=Fo (exp2-ready arguments).
        float hh[2][16];
        #pragma unroll
        for (int u = 0; u < 2; ++u)
            #pragma unroll
            for (int r = 0; r < 16; ++r) {
                const float ei = EX2(acc[u][0][r]);        // e^{-i}
                const float ef = EX2(acc[u][1][r]);        // e^{-f}
                const float eg = EX2(acc[u][2][r]);        // e^{-2g}
                const float eo = EX2(acc[u][3][r]);        // e^{-o}
                const float r1 = __builtin_amdgcn_rcpf((1.0f + ei) * (1.0f + eg));
                const float tg = (1.0f - eg) * r1;         // sig(i)*tanh(g)
                const float rf = __builtin_amdgcn_rcpf(1.0f + ef);
                const float cn = __builtin_fmaf(cc[u][r], rf, tg);
                cc[u][r] = cn;
                const float ec = EX2(cn * -2.8853900817779268f);  // e^{-2cn}
                const float r2 = __builtin_amdgcn_rcpf((1.0f + ec) * (1.0f + eo));
                hh[u][r] = (1.0f - ec) * r2;               // sig(o)*tanh(cn)
            }

        // h -> B-fragments: lane-local sequential pack (k-permutation trick)
        #pragma unroll
        for (int u = 0; u < 2; ++u) {
            Bh[u][0].u.x = pkbf(hh[u][0],  hh[u][1]);  Bh[u][0].u.y = pkbf(hh[u][2],  hh[u][3]);
            Bh[u][0].u.z = pkbf(hh[u][4],  hh[u][5]);  Bh[u][0].u.w = pkbf(hh[u][6],  hh[u][7]);
            Bh[u][1].u.x = pkbf(hh[u][8],  hh[u][9]);  Bh[u][1].u.y = pkbf(hh[u][10], hh[u][11]);
            Bh[u][1].u.z = pkbf(hh[u][12], hh[u][13]); Bh[u][1].u.w = pkbf(hh[u][14], hh[u][15]);
        }

        // projection tile: x_s = Wout*h_new + bout, then NT store
        #pragma unroll
        for (int u = 0; u < 2; ++u) {
            f32x16 px;
            px = __builtin_amdgcn_mfma_f32_32x32x16_bf16(A[4][2].b, Bbias.b,    vzero, 0, 0, 0);
            px = __builtin_amdgcn_mfma_f32_32x32x16_bf16(A[4][0].b, Bh[u][0].b, px,    0, 0, 0);
            px = __builtin_amdgcn_mfma_f32_32x32x16_bf16(A[4][1].b, Bh[u][1].b, px,    0, 0, 0);
            float* op = out + ((size_t)bgs[u] * S + s) * P + 4 * hi;
            f32x4 v0; v0.x = px[0]; v0.y = px[1]; v0.z = px[2]; v0.w = px[3];
            f32x4 v1; v1.x = px[4]; v1.y = px[5]; v1.z = px[6]; v1.w = px[7];
            __builtin_nontemporal_store(v0, reinterpret_cast<f32x4*>(op));
            __builtin_nontemporal_store(v1, reinterpret_cast<f32x4*>(op + 8));
        }

        // next step's gates (combined weights; bias chunk first in chain)
        if (s + 1 < S) {
            #pragma unroll
            for (int u = 0; u < 2; ++u)
                #pragma unroll
                for (int t = 0; t < 4; ++t)
                    acc[u][t] = __builtin_amdgcn_mfma_f32_32x32x16_bf16(A[t][2].b, Bbias.b, vzero, 0, 0, 0);
            #pragma unroll
            for (int ch = 0; ch < 2; ++ch)
                #pragma unroll
                for (int t = 0; t < 4; ++t)
                    #pragma unroll
                    for (int u = 0; u < 2; ++u)
                        acc[u][t] = __builtin_amdgcn_mfma_f32_32x32x16_bf16(A[t][ch].b, Bh[u][ch].b, acc[u][t], 0, 0, 0);
        }
    }
}

extern "C" void kernel_launch(void* const* d_in, const int* in_sizes, int n_in,
                              void* d_out, int out_size, void* d_ws, size_t ws_size,
                              hipStream_t stream) {
    const float* x0   = (const float*)d_in[0];
    const float* h0   = (const float*)d_in[1];
    const float* c0   = (const float*)d_in[2];
    const float* Wih  = (const float*)d_in[3];
    const float* Whh  = (const float*)d_in[4];
    const float* bih  = (const float*)d_in[5];
    const float* bhh  = (const float*)d_in[6];
    const float* Wout = (const float*)d_in[7];
    const float* bout = (const float*)d_in[8];
    float* out = (float*)d_out;
    unsigned int* ws = (unsigned int*)d_ws;

    const int batch = in_sizes[0] / P;  // 262144

    hipLaunchKernelGGL(setup_frags, dim3(1), dim3(256), 0, stream,
                       Wih, Whh, bih, bhh, Wout, bout, ws);

    dim3 block(256);                    // 4 waves x 64 batch rows = 256 batch/block
    dim3 grid((batch + 255) / 256);     // 1024 blocks
    hipLaunchKernelGGL(decoder_mfma, grid, block, 0, stream,
                       x0, h0, c0, ws, out, batch);
}

// Round 8
// 224.867 us; speedup vs baseline: 14.2290x; 1.0003x over previous
//
#include <hip/hip_runtime.h>
#include <hip/hip_bf16.h>

// Autoregressive LSTM decoder via bf16 MFMA, torch gate order (i,f,g,o).
// B=262144, P=16, H=32, S=25.  One wave = TWO independent 32-batch tiles.
//
// Round-8 structure:
//  * STAGGERED chains: per step, EW0 -> [proj0+gates0 MFMA] -> EW1 ->
//    [proj1+gates1 MFMA].  Each tile's gates->elementwise join gets a full
//    opposite-tile VALU phase of slack (round 7 ran both tiles in lockstep
//    and stalled both at the same join).
//  * f32x2 packed elementwise (v_pk_add/mul/fma_f32): halves main VALU issue.
//  * Carried: k-permutation (lane-local B-pack, no shuffles), exp2 scales
//    folded into A, shared-denominator sigmoid*tanh (5 exp + 3 rcp / elem).

constexpr int P = 16;
constexpr int H = 32;
constexpr int S = 25;

typedef short        bf16x8 __attribute__((ext_vector_type(8)));
typedef float        f32x16 __attribute__((ext_vector_type(16)));
typedef float        f32x4  __attribute__((ext_vector_type(4)));
typedef float        f32x2  __attribute__((ext_vector_type(2)));
typedef unsigned int u32x4  __attribute__((ext_vector_type(4)));

union FragU { u32x4 u; bf16x8 b; };

#if __has_builtin(__builtin_amdgcn_exp2f)
#define EX2 __builtin_amdgcn_exp2f
#else
#define EX2 exp2f
#endif

__device__ __forceinline__ unsigned int pkbf(float lo, float hi) {
    unsigned short a = __builtin_bit_cast(unsigned short, __float2bfloat16(lo));
    unsigned short b = __builtin_bit_cast(unsigned short, __float2bfloat16(hi));
    return (unsigned int)a | ((unsigned int)b << 16);
}

// gate-row exp2 scale: rows [0,32)=i, [32,64)=f, [64,96)=g, [96,128)=o
__device__ __forceinline__ float gate_scale(int r) {
    return (r >= 64 && r < 96) ? -2.8853900817779268f   // g rows: -2*log2(e)
                               : -1.4426950408889634f;  // i,f,o rows: -log2(e)
}

// ---------------- setup: build bf16 A-fragments into ws -------------------
// steady W_aug[160][48]: r<128: Wcomb=Whh+Wih*Wout (k<32), bias at k=32, 0 pad;
//                        128<=r<144: Wout rows, bout at k=32; r>=144: 0.
//                        gate rows (r<128) scaled by gate_scale(r).
// step0  W0_aug[128][64]: k<16: Wih; 16<=k<48: Whh; k=48: b_ih+b_hh; 0 pad.
// fragment slot: logical k = 16c + 8*(v>>1) + 4*hi + 2*(v&1) + b
// word index: steady ((t*3+c)*64 + lane)*4 + v   (t<5,c<3)
//             step0  3840 + ((t*4+c)*64 + lane)*4 + v  (t<4,c<4)
__global__ void setup_frags(const float* __restrict__ Wih, const float* __restrict__ Whh,
                            const float* __restrict__ bih, const float* __restrict__ bhh,
                            const float* __restrict__ Wout, const float* __restrict__ bout,
                            unsigned int* __restrict__ ws)
{
    auto waug = [&](int r, int k) -> float {
        float s = (r < 128) ? gate_scale(r) : 1.0f;
        if (r < 128) {
            if (k < 32) {
                float a = Whh[r * H + k];
                for (int p = 0; p < P; ++p) a += Wih[r * P + p] * Wout[p * H + k];
                return s * a;
            }
            if (k == 32) {
                float a = bih[r] + bhh[r];
                for (int p = 0; p < P; ++p) a += Wih[r * P + p] * bout[p];
                return s * a;
            }
            return 0.0f;
        } else if (r < 144) {
            int p = r - 128;
            if (k < 32)  return Wout[p * H + k];
            if (k == 32) return bout[p];
            return 0.0f;
        }
        return 0.0f;
    };
    auto w0aug = [&](int r, int k) -> float {
        float s = gate_scale(r);
        if (k < 16)  return s * Wih[r * P + k];
        if (k < 48)  return s * Whh[r * H + (k - 16)];
        if (k == 48) return s * (bih[r] + bhh[r]);
        return 0.0f;
    };

    const int tid = threadIdx.x;
    for (int idx = tid; idx < 5 * 3 * 64 * 4; idx += 256) {
        int v = idx & 3, l = (idx >> 2) & 63, tc = idx >> 8;
        int t = tc / 3, c = tc % 3;
        int r = 32 * t + (l & 31);
        int k = 16 * c + 8 * (v >> 1) + 4 * (l >> 5) + 2 * (v & 1);
        ws[idx] = pkbf(waug(r, k), waug(r, k + 1));
    }
    for (int idx = tid; idx < 4 * 4 * 64 * 4; idx += 256) {
        int v = idx & 3, l = (idx >> 2) & 63, tc = idx >> 8;
        int t = tc / 4, c = tc % 4;
        int r = 32 * t + (l & 31);
        int k = 16 * c + 8 * (v >> 1) + 4 * (l >> 5) + 2 * (v & 1);
        ws[3840 + idx] = pkbf(w0aug(r, k), w0aug(r, k + 1));
    }
}

// ------------------------------- main -------------------------------------
__global__ __launch_bounds__(256, 2) void decoder_mfma(
    const float* __restrict__ x0, const float* __restrict__ h0,
    const float* __restrict__ c0, const unsigned int* __restrict__ ws,
    float* __restrict__ out, int batch)
{
    const int lane = threadIdx.x & 63;
    const int wid  = threadIdx.x >> 6;
    const int bcol = lane & 31;
    const int hi   = lane >> 5;
    const int base = (blockIdx.x * 4 + wid) * 64;   // 64 batch rows per wave
    const int bg0  = base + bcol;
    const int bg1  = base + 32 + bcol;
    if (bg1 >= batch) return;  // batch % 256 == 0: wave-uniform

    // steady A-fragments: 5 tiles (4 gate quarters + proj) x 3 K-chunks
    FragU A[5][3];
    #pragma unroll
    for (int t = 0; t < 5; ++t)
        #pragma unroll
        for (int c = 0; c < 3; ++c)
            A[t][c].u = *reinterpret_cast<const u32x4*>(ws + ((t * 3 + c) * 64 + lane) * 4);

    // bias B-chunk: logical k=32 (steady) / k=48 (step0) at (hi=0, v=0, lo half)
    FragU Bbias;
    Bbias.u.x = (hi == 0) ? 0x3F80u : 0u;  // bf16(1.0)
    Bbias.u.y = 0u; Bbias.u.z = 0u; Bbias.u.w = 0u;

    // cell state in D-layout pairs: cc[i] = (c[row(2i)], c[row(2i+1)])
    f32x2 cc0[8], cc1[8];
    #pragma unroll
    for (int q = 0; q < 4; ++q) {
        f32x4 t0 = *reinterpret_cast<const f32x4*>(c0 + (size_t)bg0 * H + q * 8 + 4 * hi);
        cc0[2 * q]     = f32x2{t0.x, t0.y};
        cc0[2 * q + 1] = f32x2{t0.z, t0.w};
        f32x4 t1 = *reinterpret_cast<const f32x4*>(c0 + (size_t)bg1 * H + q * 8 + 4 * hi);
        cc1[2 * q]     = f32x2{t1.x, t1.y};
        cc1[2 * q + 1] = f32x2{t1.z, t1.w};
    }

    const f32x16 vzero = {};
    f32x16 acc0[4], acc1[4];

    // ---------------- helper phases (all compile-time indexed) ------------
    auto EW = [&](f32x16 (&acc)[4], f32x2 (&cc)[8], f32x2 (&hh)[8]) {
        const f32x2 one = {1.0f, 1.0f};
        const f32x2 nk2 = {-2.8853900817779268f, -2.8853900817779268f};
        #pragma unroll
        for (int i = 0; i < 8; ++i) {
            f32x2 Fi = {acc[0][2 * i], acc[0][2 * i + 1]};
            f32x2 Ff = {acc[1][2 * i], acc[1][2 * i + 1]};
            f32x2 Fg = {acc[2][2 * i], acc[2][2 * i + 1]};
            f32x2 Fo = {acc[3][2 * i], acc[3][2 * i + 1]};
            f32x2 ei, ef, eg, eo;
            ei.x = EX2(Fi.x); ei.y = EX2(Fi.y);      // e^{-i}
            ef.x = EX2(Ff.x); ef.y = EX2(Ff.y);      // e^{-f}
            eg.x = EX2(Fg.x); eg.y = EX2(Fg.y);      // e^{-2g}
            eo.x = EX2(Fo.x); eo.y = EX2(Fo.y);      // e^{-o}
            f32x2 d1 = (one + ei) * (one + eg);
            f32x2 r1; r1.x = __builtin_amdgcn_rcpf(d1.x); r1.y = __builtin_amdgcn_rcpf(d1.y);
            f32x2 tg = (one - eg) * r1;              // sig(i)*tanh(g)
            f32x2 df = one + ef;
            f32x2 rf; rf.x = __builtin_amdgcn_rcpf(df.x); rf.y = __builtin_amdgcn_rcpf(df.y);
            f32x2 cn = cc[i] * rf + tg;              // pk_fma
            cc[i] = cn;
            f32x2 ar = cn * nk2;
            f32x2 ec; ec.x = EX2(ar.x); ec.y = EX2(ar.y);   // e^{-2cn}
            f32x2 d2 = (one + ec) * (one + eo);
            f32x2 r2; r2.x = __builtin_amdgcn_rcpf(d2.x); r2.y = __builtin_amdgcn_rcpf(d2.y);
            hh[i] = (one - ec) * r2;                 // sig(o)*tanh(cn)
        }
    };
    auto PACK = [&](f32x2 (&hh)[8], FragU (&Bh)[2]) {
        Bh[0].u.x = pkbf(hh[0].x, hh[0].y); Bh[0].u.y = pkbf(hh[1].x, hh[1].y);
        Bh[0].u.z = pkbf(hh[2].x, hh[2].y); Bh[0].u.w = pkbf(hh[3].x, hh[3].y);
        Bh[1].u.x = pkbf(hh[4].x, hh[4].y); Bh[1].u.y = pkbf(hh[5].x, hh[5].y);
        Bh[1].u.z = pkbf(hh[6].x, hh[6].y); Bh[1].u.w = pkbf(hh[7].x, hh[7].y);
    };
    auto PROJSTORE = [&](FragU (&Bh)[2], int bg, int s) {
        f32x16 px;
        px = __builtin_amdgcn_mfma_f32_32x32x16_bf16(A[4][2].b, Bbias.b, vzero, 0, 0, 0);
        px = __builtin_amdgcn_mfma_f32_32x32x16_bf16(A[4][0].b, Bh[0].b, px,    0, 0, 0);
        px = __builtin_amdgcn_mfma_f32_32x32x16_bf16(A[4][1].b, Bh[1].b, px,    0, 0, 0);
        float* op = out + ((size_t)bg * S + s) * P + 4 * hi;
        f32x4 v0 = {px[0], px[1], px[2], px[3]};
        f32x4 v1 = {px[4], px[5], px[6], px[7]};
        __builtin_nontemporal_store(v0, reinterpret_cast<f32x4*>(op));
        __builtin_nontemporal_store(v1, reinterpret_cast<f32x4*>(op + 8));
    };
    auto GATES = [&](f32x16 (&acc)[4], FragU (&Bh)[2]) {
        #pragma unroll
        for (int t = 0; t < 4; ++t) {
            f32x16 a;
            a = __builtin_amdgcn_mfma_f32_32x32x16_bf16(A[t][2].b, Bbias.b, vzero, 0, 0, 0);
            a = __builtin_amdgcn_mfma_f32_32x32x16_bf16(A[t][0].b, Bh[0].b, a,    0, 0, 0);
            a = __builtin_amdgcn_mfma_f32_32x32x16_bf16(A[t][1].b, Bh[1].b, a,    0, 0, 0);
            acc[t] = a;
        }
    };

    // ---- step-0 gates: K = [x0(16) | h0(32) | 1], W0_aug fragments ----
    {
        FragU B00[4], B01[4];
        {
            const float* p = x0 + (size_t)bg0 * P;
            f32x4 a  = *reinterpret_cast<const f32x4*>(p + 4 * hi);
            f32x4 b4 = *reinterpret_cast<const f32x4*>(p + 8 + 4 * hi);
            B00[0].u.x = pkbf(a.x, a.y);   B00[0].u.y = pkbf(a.z, a.w);
            B00[0].u.z = pkbf(b4.x, b4.y); B00[0].u.w = pkbf(b4.z, b4.w);
            p = x0 + (size_t)bg1 * P;
            a  = *reinterpret_cast<const f32x4*>(p + 4 * hi);
            b4 = *reinterpret_cast<const f32x4*>(p + 8 + 4 * hi);
            B01[0].u.x = pkbf(a.x, a.y);   B01[0].u.y = pkbf(a.z, a.w);
            B01[0].u.z = pkbf(b4.x, b4.y); B01[0].u.w = pkbf(b4.z, b4.w);
        }
        #pragma unroll
        for (int ch = 0; ch < 2; ++ch) {
            const float* q = h0 + (size_t)bg0 * H + 16 * ch;
            f32x4 c4 = *reinterpret_cast<const f32x4*>(q + 4 * hi);
            f32x4 d4 = *reinterpret_cast<const f32x4*>(q + 8 + 4 * hi);
            B00[1 + ch].u.x = pkbf(c4.x, c4.y); B00[1 + ch].u.y = pkbf(c4.z, c4.w);
            B00[1 + ch].u.z = pkbf(d4.x, d4.y); B00[1 + ch].u.w = pkbf(d4.z, d4.w);
            q = h0 + (size_t)bg1 * H + 16 * ch;
            c4 = *reinterpret_cast<const f32x4*>(q + 4 * hi);
            d4 = *reinterpret_cast<const f32x4*>(q + 8 + 4 * hi);
            B01[1 + ch].u.x = pkbf(c4.x, c4.y); B01[1 + ch].u.y = pkbf(c4.z, c4.w);
            B01[1 + ch].u.z = pkbf(d4.x, d4.y); B01[1 + ch].u.w = pkbf(d4.z, d4.w);
        }
        B00[3] = Bbias; B01[3] = Bbias;
        #pragma unroll
        for (int t = 0; t < 4; ++t) { acc0[t] = vzero; acc1[t] = vzero; }
        #pragma unroll
        for (int c4 = 0; c4 < 4; ++c4)
            #pragma unroll
            for (int t = 0; t < 4; ++t) {
                FragU a;  // shared between both tiles
                a.u = *reinterpret_cast<const u32x4*>(ws + 3840 + ((t * 4 + c4) * 64 + lane) * 4);
                acc0[t] = __builtin_amdgcn_mfma_f32_32x32x16_bf16(a.b, B00[c4].b, acc0[t], 0, 0, 0);
                acc1[t] = __builtin_amdgcn_mfma_f32_32x32x16_bf16(a.b, B01[c4].b, acc1[t], 0, 0, 0);
            }
    }

    // ---- steady loop: staggered chains ----
    for (int s = 0; s < S; ++s) {
        // phase A: elementwise + pack, tile 0 (overlaps tile1 gate MFMAs
        // issued at the end of the previous iteration)
        f32x2 hh0[8]; FragU Bh0[2];
        EW(acc0, cc0, hh0); PACK(hh0, Bh0);
        // phase B: MFMA block tile 0 (proj + next gates) -- overlapped by C
        PROJSTORE(Bh0, bg0, s);
        if (s + 1 < S) GATES(acc0, Bh0);
        // phase C: elementwise + pack, tile 1
        f32x2 hh1[8]; FragU Bh1[2];
        EW(acc1, cc1, hh1); PACK(hh1, Bh1);
        // phase D: MFMA block tile 1 -- overlapped by next iteration's A
        PROJSTORE(Bh1, bg1, s);
        if (s + 1 < S) GATES(acc1, Bh1);
    }
}

extern "C" void kernel_launch(void* const* d_in, const int* in_sizes, int n_in,
                              void* d_out, int out_size, void* d_ws, size_t ws_size,
                              hipStream_t stream) {
    const float* x0   = (const float*)d_in[0];
    const float* h0   = (const float*)d_in[1];
    const float* c0   = (const float*)d_in[2];
    const float* Wih  = (const float*)d_in[3];
    const float* Whh  = (const float*)d_in[4];
    const float* bih  = (const float*)d_in[5];
    const float* bhh  = (const float*)d_in[6];
    const float* Wout = (const float*)d_in[7];
    const float* bout = (const float*)d_in[8];
    float* out = (float*)d_out;
    unsigned int* ws = (unsigned int*)d_ws;

    const int batch = in_sizes[0] / P;  // 262144

    hipLaunchKernelGGL(setup_frags, dim3(1), dim3(256), 0, stream,
                       Wih, Whh, bih, bhh, Wout, bout, ws);

    dim3 block(256);                    // 4 waves x 64 batch rows = 256 batch/block
    dim3 grid((batch + 255) / 256);     // 1024 blocks
    hipLaunchKernelGGL(decoder_mfma, grid, block, 0, stream,
                       x0, h0, c0, ws, out, batch);
}